// Round 1
// baseline (84.033 us; speedup 1.0000x reference)
//
#include <hip/hip_runtime.h>
#include <math.h>

#define LOG2PI 1.8378770664093453f
#define NSTATES 136
#define NROWS 5120   // 512 * 10
#define DIM 64
#define NCLUST 16

__device__ __forceinline__ float ndtrf(float x) {
    // ndtr(x) = 0.5 * erfc(-x / sqrt(2))
    return 0.5f * erfcf(-x * 0.70710678118654752f);
}

// ---------------------------------------------------------------------------
// Kernel 0: per-state constants (once, 1 block).
//   k0[s] = {c1 = a1.muB, nb2 = |muB|^2, recip = 1/inv_sig (0 if inv_sig==0), sd = sqrt(inv_sig+1e-12)}
//   k1[s] = {lcomb = log_pi - 31.5*LOG2PI - 0.5*log(inv_sig+1e-12), lzero = log_pi - 32*LOG2PI, 0, 0}
// ---------------------------------------------------------------------------
__global__ __launch_bounds__(256) void state_consts_kernel(
    const float* __restrict__ mu,   // [64*16] row-major [d][c]
    const float* __restrict__ pi,   // [136]
    const int* __restrict__ A, const int* __restrict__ B,
    float4* __restrict__ k0, float4* __restrict__ k1)
{
    __shared__ float musm[DIM * NCLUST];
    __shared__ float pis[NSTATES];
    __shared__ float sm_m, sm_z;
    int tid = threadIdx.x;
    for (int i = tid; i < DIM * NCLUST; i += 256) musm[i] = mu[i];
    if (tid < NSTATES) pis[tid] = pi[tid];
    __syncthreads();
    if (tid == 0) {
        float m = -1e30f;
        for (int s = 0; s < NSTATES; ++s) m = fmaxf(m, pis[s]);
        float zz = 0.f;
        for (int s = 0; s < NSTATES; ++s) zz += expf(pis[s] - m);
        sm_m = m; sm_z = zz;
    }
    __syncthreads();
    if (tid < NSTATES) {
        int a = A[tid], b = B[tid];
        float c1 = 0.f, nb2 = 0.f, iv = 0.f;
        for (int d = 0; d < DIM; ++d) {
            float mA = musm[d * NCLUST + a];
            float mB = musm[d * NCLUST + b];
            float a1 = mB - mA;
            c1  += a1 * mB;
            nb2 += mB * mB;
            iv  += a1 * a1;
        }
        float recip  = (iv == 0.f) ? 0.f : 1.f / iv;
        float sd     = sqrtf(iv + 1e-12f);
        float loginv = logf(iv + 1e-12f);
        float lp     = logf(expf(pis[tid] - sm_m) / sm_z + 1e-12f);
        float lcomb  = lp - 31.5f * LOG2PI - 0.5f * loginv;
        float lzero  = lp - 32.0f * LOG2PI;
        k0[tid] = make_float4(c1, nb2, recip, sd);
        k1[tid] = make_float4(lcomb, lzero, 0.f, 0.f);
    }
}

// ---------------------------------------------------------------------------
// Main kernel: 640 blocks x 256 threads; each wave handles 2 rows.
// Phase A: colz[c] = z . mu[:,c] for c in [0,16), plus |z|^2, via
//          lane=(chunk,c) partial dots + shfl_xor(16,32) reduction.
// Phase B: 3 states per lane; dynamic shfl gathers colz[A],colz[B];
//          wave-wide logsumexp; one atomicAdd per block.
// ---------------------------------------------------------------------------
__global__ __launch_bounds__(256) void latent_main_kernel(
    const float* __restrict__ z,    // [5120*64]
    const float* __restrict__ mu,   // [64*16]
    const int* __restrict__ A, const int* __restrict__ B,
    const float4* __restrict__ k0g, const float4* __restrict__ k1g,
    float* __restrict__ out)
{
    __shared__ float muT[NCLUST][68];     // transposed, pad 68: float4 reads, 2-way conflicts only (free)
    __shared__ float4 k0s[NSTATES];
    __shared__ float4 k1s[NSTATES];
    __shared__ int2  abs_[NSTATES];
    __shared__ float redbuf[4];

    int tid = threadIdx.x;
    // stage mu transposed: coalesced global read, scattered (conflict-free) LDS write
    for (int i = tid; i < DIM * NCLUST; i += 256) {
        int d = i >> 4, c = i & 15;
        muT[c][d] = mu[i];
    }
    if (tid < NSTATES) {
        k0s[tid] = k0g[tid];
        k1s[tid] = k1g[tid];
        abs_[tid] = make_int2(A[tid], B[tid]);
    }
    __syncthreads();

    int w = tid >> 6, lane = tid & 63;
    int chunk = lane >> 4, c = lane & 15;
    int gw = blockIdx.x * 4 + w;          // global wave id, 0..2559

    float acc = 0.f;
    #pragma unroll
    for (int rr = 0; rr < 2; ++rr) {
        int r = gw * 2 + rr;              // row in [0, 5120)

        // ---- Phase A: column dots ----
        const float4* zp = (const float4*)(z + (size_t)r * DIM + chunk * 16);
        const float4* mp = (const float4*)(&muT[c][chunk * 16]);
        float dotc = 0.f, zn = 0.f;
        #pragma unroll
        for (int i = 0; i < 4; ++i) {
            float4 z4 = zp[i];
            float4 m4 = mp[i];
            dotc += z4.x * m4.x + z4.y * m4.y + z4.z * m4.z + z4.w * m4.w;
            zn   += z4.x * z4.x + z4.y * z4.y + z4.z * z4.z + z4.w * z4.w;
        }
        // reduce across the 4 chunks (lanes c, c+16, c+32, c+48)
        dotc += __shfl_xor(dotc, 16);
        dotc += __shfl_xor(dotc, 32);
        zn   += __shfl_xor(zn, 16);
        zn   += __shfl_xor(zn, 32);
        // now: lane l holds colz[l & 15]; zn is full |z|^2 in every lane

        // ---- Phase B: per-state values + logsumexp ----
        float vmax = -INFINITY;
        float vals[3];
        #pragma unroll
        for (int it = 0; it < 3; ++it) {
            int s = it * 64 + lane;
            bool valid = (s < NSTATES);
            int ss = valid ? s : 0;
            int2 ab = abs_[ss];
            float4 K0 = k0s[ss];
            float4 K1 = k1s[ss];
            float cza = __shfl(dotc, ab.x);   // colz[A[s]]  (A[s] < 16, lane A[s] holds it)
            float czb = __shfl(dotc, ab.y);   // colz[B[s]]
            float dot = czb - cza - K0.x;     // a1 . a2
            float sq  = zn - 2.f * czb + K0.y; // |a2|^2
            // non-degenerate branch
            float mu_ = -dot * K0.z;
            float t   = -sq + dot * dot * K0.z; // _mu^2*inv_sig == dot^2*recip
            float dcdf = ndtrf((1.f - mu_) * K0.w) - ndtrf(-mu_ * K0.w);
            float v_n = K1.x + 0.5f * t + logf(dcdf + 1e-12f);
            // degenerate (inv_sig == 0) branch
            float v_z = K1.y - 0.5f * sq;
            float v = (K0.z == 0.f) ? v_z : v_n;
            if (!valid) v = -INFINITY;
            vals[it] = v;
            vmax = fmaxf(vmax, v);
        }
        #pragma unroll
        for (int m = 1; m < 64; m <<= 1) vmax = fmaxf(vmax, __shfl_xor(vmax, m));
        float se = expf(vals[0] - vmax) + expf(vals[1] - vmax) + expf(vals[2] - vmax);
        #pragma unroll
        for (int m = 1; m < 64; m <<= 1) se += __shfl_xor(se, m);
        acc += vmax + logf(se);               // identical in all lanes
    }

    if (lane == 0) redbuf[w] = acc;
    __syncthreads();
    if (tid == 0) {
        float t = redbuf[0] + redbuf[1] + redbuf[2] + redbuf[3];
        atomicAdd(out, t * (1.0f / (float)NROWS));
    }
}

extern "C" void kernel_launch(void* const* d_in, const int* in_sizes, int n_in,
                              void* d_out, int out_size, void* d_ws, size_t ws_size,
                              hipStream_t stream) {
    const float* z  = (const float*)d_in[0];
    const float* mu = (const float*)d_in[1];
    const float* pi = (const float*)d_in[2];
    const int*   A  = (const int*)d_in[3];
    const int*   B  = (const int*)d_in[4];
    float* out = (float*)d_out;

    float4* k0 = (float4*)d_ws;            // 136 * 16 B
    float4* k1 = k0 + NSTATES;             // 136 * 16 B

    hipMemsetAsync(d_out, 0, sizeof(float), stream);
    state_consts_kernel<<<1, 256, 0, stream>>>(mu, pi, A, B, k0, k1);
    latent_main_kernel<<<640, 256, 0, stream>>>(z, mu, A, B, k0, k1, out);
}

// Round 2
// 79.251 us; speedup vs baseline: 1.0603x; 1.0603x over previous
//
#include <hip/hip_runtime.h>
#include <math.h>

#define LOG2PI 1.8378770664093453f
#define NSTATES 136
#define NROWS 5120   // 512 * 10
#define DIM 64
#define NCLUST 16
#define NEG_BIG -1e30f

__device__ __forceinline__ float ndtrf(float x) {
    // ndtr(x) = 0.5 * erfc(-x / sqrt(2))
    return 0.5f * erfcf(-x * 0.70710678118654752f);
}

// ---------------------------------------------------------------------------
// Kernel 0: per-state constants (1 block) + zero d_out (replaces memset launch).
//   k0[s] = {c1 = a1.muB, nb2 = |muB|^2, recip = 1/inv_sig (0 if inv_sig==0), sd = sqrt(inv_sig+1e-12)}
//   k1[s] = {lcomb = log_pi - 31.5*LOG2PI - 0.5*log(inv_sig+1e-12), lzero = log_pi - 32*LOG2PI}
// ---------------------------------------------------------------------------
__global__ __launch_bounds__(256) void state_consts_kernel(
    const float* __restrict__ mu,   // [64*16] row-major [d][c]
    const float* __restrict__ pi,   // [136]
    const int* __restrict__ A, const int* __restrict__ B,
    float4* __restrict__ k0, float4* __restrict__ k1,
    float* __restrict__ out)
{
    __shared__ float musm[DIM * NCLUST];
    __shared__ float pis[NSTATES];
    __shared__ float sm_m, sm_z;
    int tid = threadIdx.x;
    if (tid == 0) out[0] = 0.f;          // zero accumulator for main kernel's atomics
    for (int i = tid; i < DIM * NCLUST; i += 256) musm[i] = mu[i];
    if (tid < NSTATES) pis[tid] = pi[tid];
    __syncthreads();
    if (tid < 64) {                       // wave-0 parallel softmax denom
        float m = NEG_BIG;
        for (int i = tid; i < NSTATES; i += 64) m = fmaxf(m, pis[i]);
        #pragma unroll
        for (int d = 1; d < 64; d <<= 1) m = fmaxf(m, __shfl_xor(m, d));
        float s = 0.f;
        for (int i = tid; i < NSTATES; i += 64) s += expf(pis[i] - m);
        #pragma unroll
        for (int d = 1; d < 64; d <<= 1) s += __shfl_xor(s, d);
        if (tid == 0) { sm_m = m; sm_z = s; }
    }
    __syncthreads();
    if (tid < NSTATES) {
        int a = A[tid], b = B[tid];
        float c1 = 0.f, nb2 = 0.f, iv = 0.f;
        for (int d = 0; d < DIM; ++d) {
            float mA = musm[d * NCLUST + a];
            float mB = musm[d * NCLUST + b];
            float a1 = mB - mA;
            c1  += a1 * mB;
            nb2 += mB * mB;
            iv  += a1 * a1;
        }
        float recip  = (iv == 0.f) ? 0.f : 1.f / iv;
        float sd     = sqrtf(iv + 1e-12f);
        float loginv = logf(iv + 1e-12f);
        float lp     = logf(expf(pis[tid] - sm_m) / sm_z + 1e-12f);
        float lcomb  = lp - 31.5f * LOG2PI - 0.5f * loginv;
        float lzero  = lp - 32.0f * LOG2PI;
        k0[tid] = make_float4(c1, nb2, recip, sd);
        k1[tid] = make_float4(lcomb, lzero, 0.f, 0.f);
    }
}

// ---------------------------------------------------------------------------
// Main kernel: 640 blocks x 256 threads; each wave handles 2 rows.
// Phase A: colz[c] = z . mu[:,c] for c in [0,16), plus |z|^2, via
//          lane=(chunk,c) partial dots + shfl_xor(16,32) reduction.
// Phase B: 3 states per lane; dynamic shfl gathers colz[A],colz[B];
//          online-softmax wave logsumexp (6 dependent rounds, not 12);
//          one atomicAdd per block.
// ---------------------------------------------------------------------------
__global__ __launch_bounds__(256) void latent_main_kernel(
    const float* __restrict__ z,    // [5120*64]
    const float* __restrict__ mu,   // [64*16]
    const int* __restrict__ A, const int* __restrict__ B,
    const float4* __restrict__ k0g, const float4* __restrict__ k1g,
    float* __restrict__ out)
{
    __shared__ float muT[NCLUST][68];     // transposed, pad 68: float4 reads, 2-way conflicts only (free)
    __shared__ float4 k0s[NSTATES];
    __shared__ float4 k1s[NSTATES];
    __shared__ int2  abs_[NSTATES];
    __shared__ float redbuf[4];

    int tid = threadIdx.x;
    for (int i = tid; i < DIM * NCLUST; i += 256) {
        int d = i >> 4, c = i & 15;
        muT[c][d] = mu[i];
    }
    if (tid < NSTATES) {
        k0s[tid] = k0g[tid];
        k1s[tid] = k1g[tid];
        abs_[tid] = make_int2(A[tid], B[tid]);
    }
    __syncthreads();

    int w = tid >> 6, lane = tid & 63;
    int chunk = lane >> 4, c = lane & 15;
    int gw = blockIdx.x * 4 + w;          // global wave id, 0..2559

    float acc = 0.f;
    #pragma unroll
    for (int rr = 0; rr < 2; ++rr) {
        int r = gw * 2 + rr;              // row in [0, 5120)

        // ---- Phase A: column dots ----
        const float4* zp = (const float4*)(z + (size_t)r * DIM + chunk * 16);
        const float4* mp = (const float4*)(&muT[c][chunk * 16]);
        float dotc = 0.f, zn = 0.f;
        #pragma unroll
        for (int i = 0; i < 4; ++i) {
            float4 z4 = zp[i];
            float4 m4 = mp[i];
            dotc += z4.x * m4.x + z4.y * m4.y + z4.z * m4.z + z4.w * m4.w;
            zn   += z4.x * z4.x + z4.y * z4.y + z4.z * z4.z + z4.w * z4.w;
        }
        dotc += __shfl_xor(dotc, 16);
        dotc += __shfl_xor(dotc, 32);
        zn   += __shfl_xor(zn, 16);
        zn   += __shfl_xor(zn, 32);
        // lane l holds colz[l & 15]; zn is full |z|^2 in every lane

        // ---- Phase B: per-state values ----
        float vals[3];
        #pragma unroll
        for (int it = 0; it < 3; ++it) {
            int s = it * 64 + lane;
            bool valid = (s < NSTATES);
            int ss = valid ? s : 0;
            int2 ab = abs_[ss];
            float4 K0 = k0s[ss];
            float4 K1 = k1s[ss];
            float cza = __shfl(dotc, ab.x);   // colz[A[s]]
            float czb = __shfl(dotc, ab.y);   // colz[B[s]]
            float dot = czb - cza - K0.x;     // a1 . a2
            float sq  = zn - 2.f * czb + K0.y; // |a2|^2
            float mu_ = -dot * K0.z;
            float t   = -sq + dot * dot * K0.z;
            float dcdf = ndtrf((1.f - mu_) * K0.w) - ndtrf(-mu_ * K0.w);
            float v_n = K1.x + 0.5f * t + logf(dcdf + 1e-12f);
            float v_z = K1.y - 0.5f * sq;
            float v = (K0.z == 0.f) ? v_z : v_n;
            vals[it] = valid ? v : NEG_BIG;
        }

        // ---- online-softmax logsumexp: 6 dependent rounds ----
        float m = fmaxf(fmaxf(vals[0], vals[1]), vals[2]);
        float s = expf(vals[0] - m) + expf(vals[1] - m) + expf(vals[2] - m);
        #pragma unroll
        for (int d = 1; d < 64; d <<= 1) {
            float mo = __shfl_xor(m, d);
            float so = __shfl_xor(s, d);
            float mn = fmaxf(m, mo);
            s = s * expf(m - mn) + so * expf(mo - mn);
            m = mn;
        }
        acc += m + logf(s);               // identical in all lanes
    }

    if (lane == 0) redbuf[w] = acc;
    __syncthreads();
    if (tid == 0) {
        float t = redbuf[0] + redbuf[1] + redbuf[2] + redbuf[3];
        atomicAdd(out, t * (1.0f / (float)NROWS));
    }
}

extern "C" void kernel_launch(void* const* d_in, const int* in_sizes, int n_in,
                              void* d_out, int out_size, void* d_ws, size_t ws_size,
                              hipStream_t stream) {
    const float* z  = (const float*)d_in[0];
    const float* mu = (const float*)d_in[1];
    const float* pi = (const float*)d_in[2];
    const int*   A  = (const int*)d_in[3];
    const int*   B  = (const int*)d_in[4];
    float* out = (float*)d_out;

    float4* k0 = (float4*)d_ws;            // 136 * 16 B
    float4* k1 = k0 + NSTATES;             // 136 * 16 B

    state_consts_kernel<<<1, 256, 0, stream>>>(mu, pi, A, B, k0, k1, out);
    latent_main_kernel<<<640, 256, 0, stream>>>(z, mu, A, B, k0, k1, out);
}

// Round 3
// 74.101 us; speedup vs baseline: 1.1340x; 1.0695x over previous
//
#include <hip/hip_runtime.h>
#include <math.h>

#define LOG2PI 1.8378770664093453f
#define NSTATES 136
#define NROWS 5120   // 512 * 10
#define DIM 64
#define NCLUST 16
#define NBLOCKS 640
#define NEG_BIG -1e30f

__device__ __forceinline__ float ndtrf(float x) {
    // ndtr(x) = 0.5 * erfc(-x / sqrt(2))
    return 0.5f * erfcf(-x * 0.70710678118654752f);
}

// ---------------------------------------------------------------------------
// Fused kernel: 640 blocks x 256 threads.
//  Prologue (per block, redundant, ~0.4us, overlapped across 640 blocks):
//    stage mu (transposed) + pi + A/B into LDS; wave 3 computes pi-softmax
//    denom while tids<136 compute per-state {c1, nb2, inv_sig}; finalize
//    k0s/k1s in LDS.
//  Main: each wave handles 2 rows.
//    Phase A: colz[c] = z . mu[:,c] (16 cols) + |z|^2 via lane=(chunk,c)
//             float4 partial dots + shfl_xor(16,32).
//    Phase B: 3 states/lane; dynamic shfl gathers colz[A],colz[B];
//             online-softmax wave logsumexp (6 dependent rounds).
//  Epilogue: one float per block -> partials[bid] (no atomics, no pre-zero).
// ---------------------------------------------------------------------------
__global__ __launch_bounds__(256) void latent_fused_kernel(
    const float* __restrict__ z,    // [5120*64]
    const float* __restrict__ mu,   // [64*16] row-major [d][c]
    const float* __restrict__ pi,   // [136]
    const int* __restrict__ A, const int* __restrict__ B,
    float* __restrict__ partials)   // [640]
{
    __shared__ float muT[NCLUST][68];   // transposed, pad 68: float4 reads -> 2-way conflicts only (free)
    __shared__ float pis[NSTATES];
    __shared__ float4 k0s[NSTATES];     // {c1, nb2, recip, sd}
    __shared__ float4 k1s[NSTATES];     // {lcomb, lzero, -, -}
    __shared__ int2  abs_[NSTATES];
    __shared__ float sm_m, sm_z;
    __shared__ float redbuf[4];

    int tid = threadIdx.x;
    for (int i = tid; i < DIM * NCLUST; i += 256) {
        muT[i & 15][i >> 4] = mu[i];    // coalesced read, conflict-free scatter
    }
    if (tid < NSTATES) {
        pis[tid] = pi[tid];
        abs_[tid] = make_int2(A[tid], B[tid]);
    }
    __syncthreads();

    // ---- per-state constants (redundant per block) ----
    float c1 = 0.f, nb2 = 0.f, iv = 0.f;
    if (tid >= 192) {                   // wave 3: pi-softmax denom (others busy below)
        int l = tid - 192;
        float m = NEG_BIG;
        for (int i = l; i < NSTATES; i += 64) m = fmaxf(m, pis[i]);
        #pragma unroll
        for (int d = 1; d < 64; d <<= 1) m = fmaxf(m, __shfl_xor(m, d));
        float s = 0.f;
        for (int i = l; i < NSTATES; i += 64) s += expf(pis[i] - m);
        #pragma unroll
        for (int d = 1; d < 64; d <<= 1) s += __shfl_xor(s, d);
        if (l == 0) { sm_m = m; sm_z = s; }
    } else if (tid < NSTATES) {
        int2 ab = abs_[tid];
        for (int d = 0; d < DIM; ++d) {
            float mA = muT[ab.x][d];
            float mB = muT[ab.y][d];
            float a1 = mB - mA;
            c1  += a1 * mB;
            nb2 += mB * mB;
            iv  += a1 * a1;
        }
    }
    __syncthreads();
    if (tid < NSTATES) {
        float recip  = (iv == 0.f) ? 0.f : 1.f / iv;
        float sd     = sqrtf(iv + 1e-12f);
        float lp     = logf(expf(pis[tid] - sm_m) / sm_z + 1e-12f);
        k0s[tid] = make_float4(c1, nb2, recip, sd);
        k1s[tid] = make_float4(lp - 31.5f * LOG2PI - 0.5f * logf(iv + 1e-12f),
                               lp - 32.0f * LOG2PI, 0.f, 0.f);
    }
    __syncthreads();

    // ---- main ----
    int w = tid >> 6, lane = tid & 63;
    int chunk = lane >> 4, c = lane & 15;
    int gw = blockIdx.x * 4 + w;          // global wave id, 0..2559

    float acc = 0.f;
    #pragma unroll
    for (int rr = 0; rr < 2; ++rr) {
        int r = gw * 2 + rr;              // row in [0, 5120)

        // ---- Phase A: column dots ----
        const float4* zp = (const float4*)(z + (size_t)r * DIM + chunk * 16);
        const float4* mp = (const float4*)(&muT[c][chunk * 16]);
        float dotc = 0.f, zn = 0.f;
        #pragma unroll
        for (int i = 0; i < 4; ++i) {
            float4 z4 = zp[i];
            float4 m4 = mp[i];
            dotc += z4.x * m4.x + z4.y * m4.y + z4.z * m4.z + z4.w * m4.w;
            zn   += z4.x * z4.x + z4.y * z4.y + z4.z * z4.z + z4.w * z4.w;
        }
        dotc += __shfl_xor(dotc, 16);
        dotc += __shfl_xor(dotc, 32);
        zn   += __shfl_xor(zn, 16);
        zn   += __shfl_xor(zn, 32);
        // lane l holds colz[l & 15]; zn is full |z|^2 in every lane

        // ---- Phase B: per-state values ----
        float vals[3];
        #pragma unroll
        for (int it = 0; it < 3; ++it) {
            int s = it * 64 + lane;
            bool valid = (s < NSTATES);
            int ss = valid ? s : 0;
            int2 ab = abs_[ss];
            float4 K0 = k0s[ss];
            float4 K1 = k1s[ss];
            float cza = __shfl(dotc, ab.x);    // colz[A[s]]
            float czb = __shfl(dotc, ab.y);    // colz[B[s]]
            float dot = czb - cza - K0.x;      // a1 . a2
            float sq  = zn - 2.f * czb + K0.y; // |a2|^2
            float mu_ = -dot * K0.z;
            float t   = -sq + dot * dot * K0.z;
            float dcdf = ndtrf((1.f - mu_) * K0.w) - ndtrf(-mu_ * K0.w);
            float v_n = K1.x + 0.5f * t + logf(dcdf + 1e-12f);
            float v_z = K1.y - 0.5f * sq;
            float v = (K0.z == 0.f) ? v_z : v_n;
            vals[it] = valid ? v : NEG_BIG;
        }

        // ---- online-softmax logsumexp: 6 dependent rounds ----
        float m = fmaxf(fmaxf(vals[0], vals[1]), vals[2]);
        float s = expf(vals[0] - m) + expf(vals[1] - m) + expf(vals[2] - m);
        #pragma unroll
        for (int d = 1; d < 64; d <<= 1) {
            float mo = __shfl_xor(m, d);
            float so = __shfl_xor(s, d);
            float mn = fmaxf(m, mo);
            s = s * expf(m - mn) + so * expf(mo - mn);
            m = mn;
        }
        acc += m + logf(s);               // identical in all lanes
    }

    if (lane == 0) redbuf[w] = acc;
    __syncthreads();
    if (tid == 0) {
        partials[blockIdx.x] = redbuf[0] + redbuf[1] + redbuf[2] + redbuf[3];
    }
}

// ---------------------------------------------------------------------------
// Tail: sum 640 partials -> out[0] = sum / 5120. One tiny block.
// ---------------------------------------------------------------------------
__global__ __launch_bounds__(256) void final_reduce_kernel(
    const float* __restrict__ partials, float* __restrict__ out)
{
    __shared__ float rb[4];
    int tid = threadIdx.x;
    float s = 0.f;
    for (int i = tid; i < NBLOCKS; i += 256) s += partials[i];
    #pragma unroll
    for (int d = 1; d < 64; d <<= 1) s += __shfl_xor(s, d);
    if ((tid & 63) == 0) rb[tid >> 6] = s;
    __syncthreads();
    if (tid == 0) out[0] = (rb[0] + rb[1] + rb[2] + rb[3]) * (1.0f / (float)NROWS);
}

extern "C" void kernel_launch(void* const* d_in, const int* in_sizes, int n_in,
                              void* d_out, int out_size, void* d_ws, size_t ws_size,
                              hipStream_t stream) {
    const float* z  = (const float*)d_in[0];
    const float* mu = (const float*)d_in[1];
    const float* pi = (const float*)d_in[2];
    const int*   A  = (const int*)d_in[3];
    const int*   B  = (const int*)d_in[4];
    float* out = (float*)d_out;
    float* partials = (float*)d_ws;       // 640 * 4 B

    latent_fused_kernel<<<NBLOCKS, 256, 0, stream>>>(z, mu, pi, A, B, partials);
    final_reduce_kernel<<<1, 256, 0, stream>>>(partials, out);
}